// Round 2
// baseline (47.073 us; speedup 1.0000x reference)
//
#include <hip/hip_runtime.h>

// Anchor decode (YOLO-style), B=32, A=3, C=14 (7 box/conf + 7 cls), G=152.
// out[b, a2, gy, gx, f] (flattened (B, A*G*G, 15)):
//   f0=im  f1=re  f2=atan(im/re)  f3=sigmoid(conf)
//   f4=floor((sigmoid(tx)+gx)*4)  f5=floor((sigmoid(ty)+gy)*4)
//   f6=exp(tw)*anchor_w[a2]       f7=exp(th)*anchor_h[a2]
//   f8..14: cc=(f-8)*3+a2; src anchor as=cc/7, cls k=cc%7 -> x[b, as*14+7+k, gy, gx]
// (class channels deliberately scrambled across anchors — matches the
//  reshape(B,15,A,G,G) of the concatenated feats in the reference.)
//
// R2: LDS as 3840 float4-granules with XOR swizzle phi(g)=g^((g>>3)&7) applied
// on both sides -> b128 writes (~<=2-way, free) + conflict-free b128 reads
// (was 8-way on 60 scalar ds_read_b32). Non-temporal global loads/stores
// (pure streaming, no reuse -> keep L2/L3 clean).

constexpr int G   = 152;
constexpr int GG  = G * G;        // 23104, %4 == 0
constexpr int Cc  = 14;
constexpr int NTHREADS  = 256;
constexpr int TILE_ROWS = 1024;   // rows (=output 15-float groups) per block

typedef float f32x4 __attribute__((ext_vector_type(4)));

__device__ __forceinline__ float sigmoidf_(float v) {
    return 1.0f / (1.0f + __expf(-v));
}
__device__ __forceinline__ int swz(int g) {      // bijective involution on granules
    return g ^ ((g >> 3) & 7);
}
__device__ __forceinline__ f32x4 ldg_nt(const float* p) {
    return __builtin_nontemporal_load((const f32x4*)p);
}

__global__ __launch_bounds__(NTHREADS) void decode_kernel(
    const float* __restrict__ x, const float* __restrict__ anchors,
    float* __restrict__ out, int total_rows)
{
    __shared__ f32x4 lds4[TILE_ROWS * 15 / 4];   // 3840 granules = 61440 B

    const int t  = threadIdx.x;
    const int r0 = blockIdx.x * TILE_ROWS + t * 4;   // 4 consecutive rows per thread

    if (r0 + 3 < total_rows) {
        const unsigned ba = (unsigned)r0 / (unsigned)GG;   // b*3 + a2 (same for all 4 rows)
        const int s0      = r0 - (int)ba * GG;             // %4 == 0
        const unsigned b  = ba / 3u;
        const int a2      = (int)(ba - b * 3u);
        const int gy      = s0 / G;
        const int gx0     = s0 - gy * G;                   // %4==0 -> no row wrap in the 4

        const float an_w = anchors[a2 * 2 + 0];
        const float an_h = anchors[a2 * 2 + 1];

        const float* xb = x + (size_t)(b * 42u) * GG + s0;
        const int cb = a2 * Cc;

        const f32x4 vtx = ldg_nt(xb + (size_t)(cb + 0) * GG);
        const f32x4 vty = ldg_nt(xb + (size_t)(cb + 1) * GG);
        const f32x4 vtw = ldg_nt(xb + (size_t)(cb + 2) * GG);
        const f32x4 vth = ldg_nt(xb + (size_t)(cb + 3) * GG);
        const f32x4 vim = ldg_nt(xb + (size_t)(cb + 4) * GG);
        const f32x4 vre = ldg_nt(xb + (size_t)(cb + 5) * GG);
        const f32x4 vcf = ldg_nt(xb + (size_t)(cb + 6) * GG);
        f32x4 vcls[7];
#pragma unroll
        for (int fc = 0; fc < 7; ++fc) {
            const int cc = fc * 3 + a2;
            const int as = cc / 7;
            const int k  = cc - as * 7;
            vcls[fc] = ldg_nt(xb + (size_t)(as * Cc + 7 + k) * GG);
        }

        float v[60];                                  // fully static-indexed -> VGPRs
#pragma unroll
        for (int u = 0; u < 4; ++u) {
            const float im  = vim[u];
            const float re  = vre[u];
            const float yaw = atanf(im / re);
            const float cf  = sigmoidf_(vcf[u]);
            const float ax  = floorf((sigmoidf_(vtx[u]) + (float)(gx0 + u)) * 4.0f);
            const float ay  = floorf((sigmoidf_(vty[u]) + (float)gy) * 4.0f);
            const float aw  = __expf(vtw[u]) * an_w;
            const float ah  = __expf(vth[u]) * an_h;
            v[u * 15 + 0] = im;  v[u * 15 + 1] = re;
            v[u * 15 + 2] = yaw; v[u * 15 + 3] = cf;
            v[u * 15 + 4] = ax;  v[u * 15 + 5] = ay;
            v[u * 15 + 6] = aw;  v[u * 15 + 7] = ah;
#pragma unroll
            for (int fc = 0; fc < 7; ++fc) v[u * 15 + 8 + fc] = vcls[fc][u];
        }
#pragma unroll
        for (int j = 0; j < 15; ++j) {
            f32x4 q = { v[4 * j], v[4 * j + 1], v[4 * j + 2], v[4 * j + 3] };
            lds4[swz(15 * t + j)] = q;                // ds_write_b128
        }
    }
    __syncthreads();

    // Coalesced non-temporal float4 store of the block's 15360-float chunk.
    const long long block_word0 = (long long)blockIdx.x * (TILE_ROWS * 15);
    const long long total_words = (long long)total_rows * 15;
    float* outp = out + block_word0;
#pragma unroll
    for (int i = 0; i < 15; ++i) {
        const int gr = i * NTHREADS + t;              // granule index within chunk
        if (block_word0 + 4 * gr + 3 < total_words) {
            f32x4 q = lds4[swz(gr)];                  // ds_read_b128, conflict-free
            __builtin_nontemporal_store(q, (f32x4*)(outp + 4 * gr));
        }
    }
}

extern "C" void kernel_launch(void* const* d_in, const int* in_sizes, int n_in,
                              void* d_out, int out_size, void* d_ws, size_t ws_size,
                              hipStream_t stream) {
    const float* x       = (const float*)d_in[0];
    const float* anchors = (const float*)d_in[1];
    float* out           = (float*)d_out;

    const int B          = in_sizes[0] / (3 * Cc * GG);   // 32
    const int total_rows = B * 3 * GG;                    // 2,217,984 (exact multiple of 1024)
    const int nblocks    = (total_rows + TILE_ROWS - 1) / TILE_ROWS;  // 2166

    hipLaunchKernelGGL(decode_kernel, dim3(nblocks), dim3(NTHREADS), 0, stream,
                       x, anchors, out, total_rows);
}

// Round 3
// 43.686 us; speedup vs baseline: 1.0775x; 1.0775x over previous
//
#include <hip/hip_runtime.h>

// Anchor decode (YOLO-style), B=32, A=3, C=14 (7 box/conf + 7 cls), G=152.
// out[b, a2, gy, gx, f] (flattened (B, A*G*G, 15)):
//   f0=im  f1=re  f2=atan(im/re)  f3=sigmoid(conf)
//   f4=floor((sigmoid(tx)+gx)*4)  f5=floor((sigmoid(ty)+gy)*4)
//   f6=exp(tw)*anchor_w[a2]       f7=exp(th)*anchor_h[a2]
//   f8..14: cc=(f-8)*3+a2; src anchor as=cc/7, cls k=cc%7 -> x[b, as*14+7+k, gy, gx]
// (class channels deliberately scrambled across anchors — matches the
//  reshape(B,15,A,G,G) of the concatenated feats in the reference.)
//
// R3: plain float4-granule LDS, NO swizzle (write granules 15t+j -> quad
// (7t+j)%8 cycles all 8 -> conflict-free; read granules consecutive ->
// conflict-free), NO non-temporal hints (R2 showed nt stores regress vs
// normal stores on gfx950; fills sustain 7.2 TB/s with plain stores).

constexpr int G   = 152;
constexpr int GG  = G * G;        // 23104, %4 == 0
constexpr int Cc  = 14;
constexpr int NTHREADS  = 256;
constexpr int TILE_ROWS = 1024;   // rows (=output 15-float groups) per block

typedef float f32x4 __attribute__((ext_vector_type(4)));

__device__ __forceinline__ float sigmoidf_(float v) {
    return 1.0f / (1.0f + __expf(-v));
}

__global__ __launch_bounds__(NTHREADS) void decode_kernel(
    const float* __restrict__ x, const float* __restrict__ anchors,
    float* __restrict__ out, int total_rows)
{
    __shared__ f32x4 lds4[TILE_ROWS * 15 / 4];   // 3840 granules = 61440 B

    const int t  = threadIdx.x;
    const int r0 = blockIdx.x * TILE_ROWS + t * 4;   // 4 consecutive rows per thread

    if (r0 + 3 < total_rows) {
        const unsigned ba = (unsigned)r0 / (unsigned)GG;   // b*3 + a2 (same for all 4 rows)
        const int s0      = r0 - (int)ba * GG;             // %4 == 0
        const unsigned b  = ba / 3u;
        const int a2      = (int)(ba - b * 3u);
        const int gy      = s0 / G;
        const int gx0     = s0 - gy * G;                   // %4==0 -> no row wrap in the 4

        const float an_w = anchors[a2 * 2 + 0];
        const float an_h = anchors[a2 * 2 + 1];

        const float* xb = x + (size_t)(b * 42u) * GG + s0;
        const int cb = a2 * Cc;

        const f32x4 vtx = *(const f32x4*)(xb + (size_t)(cb + 0) * GG);
        const f32x4 vty = *(const f32x4*)(xb + (size_t)(cb + 1) * GG);
        const f32x4 vtw = *(const f32x4*)(xb + (size_t)(cb + 2) * GG);
        const f32x4 vth = *(const f32x4*)(xb + (size_t)(cb + 3) * GG);
        const f32x4 vim = *(const f32x4*)(xb + (size_t)(cb + 4) * GG);
        const f32x4 vre = *(const f32x4*)(xb + (size_t)(cb + 5) * GG);
        const f32x4 vcf = *(const f32x4*)(xb + (size_t)(cb + 6) * GG);
        f32x4 vcls[7];
#pragma unroll
        for (int fc = 0; fc < 7; ++fc) {
            const int cc = fc * 3 + a2;
            const int as = cc / 7;
            const int k  = cc - as * 7;
            vcls[fc] = *(const f32x4*)(xb + (size_t)(as * Cc + 7 + k) * GG);
        }

        float v[60];                                  // fully static-indexed -> VGPRs
#pragma unroll
        for (int u = 0; u < 4; ++u) {
            const float im  = vim[u];
            const float re  = vre[u];
            const float yaw = atanf(im / re);
            const float cf  = sigmoidf_(vcf[u]);
            const float ax  = floorf((sigmoidf_(vtx[u]) + (float)(gx0 + u)) * 4.0f);
            const float ay  = floorf((sigmoidf_(vty[u]) + (float)gy) * 4.0f);
            const float aw  = __expf(vtw[u]) * an_w;
            const float ah  = __expf(vth[u]) * an_h;
            v[u * 15 + 0] = im;  v[u * 15 + 1] = re;
            v[u * 15 + 2] = yaw; v[u * 15 + 3] = cf;
            v[u * 15 + 4] = ax;  v[u * 15 + 5] = ay;
            v[u * 15 + 6] = aw;  v[u * 15 + 7] = ah;
#pragma unroll
            for (int fc = 0; fc < 7; ++fc) v[u * 15 + 8 + fc] = vcls[fc][u];
        }
#pragma unroll
        for (int j = 0; j < 15; ++j) {
            f32x4 q = { v[4 * j], v[4 * j + 1], v[4 * j + 2], v[4 * j + 3] };
            lds4[15 * t + j] = q;                     // ds_write_b128, quad (7t+j)%8: conflict-free
        }
    }
    __syncthreads();

    // Coalesced float4 store of the block's 15360-float chunk.
    const long long block_word0 = (long long)blockIdx.x * (TILE_ROWS * 15);
    const long long total_words = (long long)total_rows * 15;
    float* outp = out + block_word0;
#pragma unroll
    for (int i = 0; i < 15; ++i) {
        const int gr = i * NTHREADS + t;              // granule index within chunk
        if (block_word0 + 4 * gr + 3 < total_words) {
            f32x4 q = lds4[gr];                       // ds_read_b128, consecutive: conflict-free
            *(f32x4*)(outp + 4 * gr) = q;
        }
    }
}

extern "C" void kernel_launch(void* const* d_in, const int* in_sizes, int n_in,
                              void* d_out, int out_size, void* d_ws, size_t ws_size,
                              hipStream_t stream) {
    const float* x       = (const float*)d_in[0];
    const float* anchors = (const float*)d_in[1];
    float* out           = (float*)d_out;

    const int B          = in_sizes[0] / (3 * Cc * GG);   // 32
    const int total_rows = B * 3 * GG;                    // 2,217,984 (exact multiple of 1024)
    const int nblocks    = (total_rows + TILE_ROWS - 1) / TILE_ROWS;  // 2166

    hipLaunchKernelGGL(decode_kernel, dim3(nblocks), dim3(NTHREADS), 0, stream,
                       x, anchors, out, total_rows);
}